// Round 1
// baseline (9428.428 us; speedup 1.0000x reference)
//
#include <hip/hip_runtime.h>

static constexpr int NN = 100000;   // nodes
static constexpr int NE = 1600000;  // edges
static constexpr int C  = 128;      // feature dim
static constexpr int OC = 10;       // output classes
static constexpr int NG = 512;      // graphs

// ---------------------------------------------------------------------------
// Edge scatter-add: agg[dst] += h[src].  32 threads per edge, float4 per thread.
// ---------------------------------------------------------------------------
__global__ void k_scatter(const float* __restrict__ h,
                          const int* __restrict__ src,
                          const int* __restrict__ dst,
                          float* __restrict__ agg) {
    int t = blockIdx.x * blockDim.x + threadIdx.x;
    int e = t >> 5;
    if (e >= NE) return;
    int lane = t & 31;
    int s = src[e];
    int d = dst[e];
    float4 v = *reinterpret_cast<const float4*>(h + (size_t)s * C + lane * 4);
    float* o = agg + (size_t)d * C + lane * 4;
    atomicAdd(o + 0, v.x);
    atomicAdd(o + 1, v.y);
    atomicAdd(o + 2, v.z);
    atomicAdd(o + 3, v.w);
}

// ---------------------------------------------------------------------------
// Fused node transform: out = [relu]( agg @ W_rel + b + h @ W_root )
// Block = 256 threads = 2 nodes x 128 output channels.
// ---------------------------------------------------------------------------
template <bool RELU>
__global__ void k_transform(const float* __restrict__ agg,
                            const float* __restrict__ h,
                            const float* __restrict__ W_rel,
                            const float* __restrict__ b,
                            const float* __restrict__ W_root,
                            float* __restrict__ out) {
    int g = threadIdx.x >> 7;          // node group within block (0/1)
    int c = threadIdx.x & 127;         // output channel
    int node = blockIdx.x * 2 + g;

    __shared__ float sa[2][C];
    __shared__ float sh[2][C];

    if (node < NN) {
        sa[g][c] = agg[(size_t)node * C + c];
        sh[g][c] = h[(size_t)node * C + c];
    }
    __syncthreads();
    if (node >= NN) return;

    float acc = b[c];
#pragma unroll 8
    for (int k = 0; k < C; ++k) {
        acc += sa[g][k] * W_rel[k * C + c];
        acc += sh[g][k] * W_root[k * C + c];
    }
    if (RELU) acc = fmaxf(acc, 0.0f);
    out[(size_t)node * C + c] = acc;
}

// ---------------------------------------------------------------------------
// Mean-pool: sums[batch[i]] += h[i], counts[batch[i]] += 1
// ---------------------------------------------------------------------------
__global__ void k_pool(const float* __restrict__ h,
                       const int* __restrict__ batch,
                       float* __restrict__ sums) {
    int t = blockIdx.x * blockDim.x + threadIdx.x;
    if (t >= NN * C) return;
    int node = t >> 7;
    int c = t & 127;
    atomicAdd(sums + batch[node] * C + c, h[t]);
}

__global__ void k_count(const int* __restrict__ batch,
                        float* __restrict__ counts) {
    int i = blockIdx.x * blockDim.x + threadIdx.x;
    if (i < NN) atomicAdd(counts + batch[i], 1.0f);
}

// ---------------------------------------------------------------------------
// Final: out[g] = (sums[g]/max(count,1)) @ W_lin + b_lin.  Block per graph.
// ---------------------------------------------------------------------------
__global__ void k_final(const float* __restrict__ sums,
                        const float* __restrict__ counts,
                        const float* __restrict__ W_lin,
                        const float* __restrict__ b_lin,
                        float* __restrict__ out) {
    int g = blockIdx.x;
    int t = threadIdx.x;
    __shared__ float sp[C];
    float cnt = fmaxf(counts[g], 1.0f);
    sp[t] = sums[(size_t)g * C + t] / cnt;
    __syncthreads();
    if (t < OC) {
        float acc = b_lin[t];
#pragma unroll 8
        for (int k = 0; k < C; ++k) acc += sp[k] * W_lin[k * OC + t];
        out[(size_t)g * OC + t] = acc;
    }
}

extern "C" void kernel_launch(void* const* d_in, const int* in_sizes, int n_in,
                              void* d_out, int out_size, void* d_ws, size_t ws_size,
                              hipStream_t stream) {
    const float* x       = (const float*)d_in[0];
    const int*   eidx    = (const int*)d_in[1];   // [2, NE] flat: row0=src, row1=dst
    const int*   batch   = (const int*)d_in[2];
    const float* W1_rel  = (const float*)d_in[3];
    const float* b1      = (const float*)d_in[4];
    const float* W1_root = (const float*)d_in[5];
    const float* W2_rel  = (const float*)d_in[6];
    const float* b2      = (const float*)d_in[7];
    const float* W2_root = (const float*)d_in[8];
    const float* W3_rel  = (const float*)d_in[9];
    const float* b3      = (const float*)d_in[10];
    const float* W3_root = (const float*)d_in[11];
    const float* W_lin   = (const float*)d_in[12];
    const float* b_lin   = (const float*)d_in[13];
    float* out = (float*)d_out;

    const int* src = eidx;
    const int* dst = eidx + NE;

    float* agg    = (float*)d_ws;                 // NN*C
    float* hA     = agg + (size_t)NN * C;         // NN*C
    float* hB     = hA + (size_t)NN * C;          // NN*C
    float* sums   = hB + (size_t)NN * C;          // NG*C
    // counts lives right after sums (zeroed together)
    float* counts = sums + (size_t)NG * C;        // NG

    const size_t nbytes_h = (size_t)NN * C * sizeof(float);

    const int scatter_blocks = (NE * 32 + 255) / 256;
    const int tr_blocks = (NN + 1) / 2;
    const int pool_blocks = (NN * C + 255) / 256;

    // ---- Layer 1 ----
    hipMemsetAsync(agg, 0, nbytes_h, stream);
    k_scatter<<<scatter_blocks, 256, 0, stream>>>(x, src, dst, agg);
    k_transform<true><<<tr_blocks, 256, 0, stream>>>(agg, x, W1_rel, b1, W1_root, hA);

    // ---- Layer 2 ----
    hipMemsetAsync(agg, 0, nbytes_h, stream);
    k_scatter<<<scatter_blocks, 256, 0, stream>>>(hA, src, dst, agg);
    k_transform<true><<<tr_blocks, 256, 0, stream>>>(agg, hA, W2_rel, b2, W2_root, hB);

    // ---- Layer 3 (no relu) ----
    hipMemsetAsync(agg, 0, nbytes_h, stream);
    k_scatter<<<scatter_blocks, 256, 0, stream>>>(hB, src, dst, agg);
    k_transform<false><<<tr_blocks, 256, 0, stream>>>(agg, hB, W3_rel, b3, W3_root, hA);

    // ---- Pool + final linear ----
    hipMemsetAsync(sums, 0, ((size_t)NG * C + NG) * sizeof(float), stream);
    k_pool<<<pool_blocks, 256, 0, stream>>>(hA, batch, sums);
    k_count<<<(NN + 255) / 256, 256, 0, stream>>>(batch, counts);
    k_final<<<NG, C, 0, stream>>>(sums, counts, W_lin, b_lin, out);
}

// Round 2
// 1799.481 us; speedup vs baseline: 5.2395x; 5.2395x over previous
//
#include <hip/hip_runtime.h>

static constexpr int NN = 100000;   // nodes
static constexpr int NE = 1600000;  // edges
static constexpr int C  = 128;      // feature dim
static constexpr int OC = 10;       // output classes
static constexpr int NG = 512;      // graphs

static constexpr int SCAN_B = 1024;
static constexpr int NB = (NN + SCAN_B - 1) / SCAN_B;  // 98

// ---------------------------------------------------------------------------
// CSR build: deg histogram -> exclusive scan -> cursor fill
// ---------------------------------------------------------------------------
__global__ void k_hist(const int* __restrict__ dst, int* __restrict__ deg) {
    int e = blockIdx.x * blockDim.x + threadIdx.x;
    if (e < NE) atomicAdd(&deg[dst[e]], 1);
}

__global__ void k_scan1(const int* __restrict__ deg, int* __restrict__ rp,
                        int* __restrict__ bsum) {
    __shared__ int buf[SCAN_B];
    int tid = threadIdx.x;
    int i = blockIdx.x * SCAN_B + tid;
    int v = (i < NN) ? deg[i] : 0;
    buf[tid] = v;
    __syncthreads();
    for (int off = 1; off < SCAN_B; off <<= 1) {
        int t = (tid >= off) ? buf[tid - off] : 0;
        __syncthreads();
        buf[tid] += t;
        __syncthreads();
    }
    if (i < NN) rp[i] = buf[tid] - v;  // exclusive
    if (tid == SCAN_B - 1) bsum[blockIdx.x] = buf[tid];
}

__global__ void k_scan2(int* __restrict__ bsum) {
    if (blockIdx.x == 0 && threadIdx.x == 0) {
        int acc = 0;
        for (int i = 0; i < NB; ++i) { int t = bsum[i]; bsum[i] = acc; acc += t; }
    }
}

__global__ void k_scan3(int* __restrict__ rp, const int* __restrict__ bsum,
                        int* __restrict__ cursor) {
    int i = blockIdx.x * SCAN_B + threadIdx.x;
    if (i < NN) {
        int v = rp[i] + bsum[i / SCAN_B];
        rp[i] = v;
        cursor[i] = v;
    }
    if (i == 0) rp[NN] = NE;
}

__global__ void k_fill(const int* __restrict__ src, const int* __restrict__ dst,
                       int* __restrict__ cursor, int* __restrict__ csr) {
    int e = blockIdx.x * blockDim.x + threadIdx.x;
    if (e < NE) {
        int p = atomicAdd(&cursor[dst[e]], 1);
        csr[p] = src[e];
    }
}

// ---------------------------------------------------------------------------
// Gather-aggregate: agg[i] = sum_{j in in(i)} h[j].  32 lanes/node, float4.
// ---------------------------------------------------------------------------
__global__ void k_gather(const float* __restrict__ h, const int* __restrict__ rp,
                         const int* __restrict__ csr, float* __restrict__ agg) {
    int t = blockIdx.x * blockDim.x + threadIdx.x;
    int node = t >> 5;
    if (node >= NN) return;
    int lane = t & 31;
    int beg = rp[node], end = rp[node + 1];
    float4 acc = {0.f, 0.f, 0.f, 0.f};
    for (int j = beg; j < end; ++j) {
        int s = csr[j];
        float4 v = *reinterpret_cast<const float4*>(h + (size_t)s * C + lane * 4);
        acc.x += v.x; acc.y += v.y; acc.z += v.z; acc.w += v.w;
    }
    *reinterpret_cast<float4*>(agg + (size_t)node * C + lane * 4) = acc;
}

// ---------------------------------------------------------------------------
// Fused node transform: out = [relu]( agg @ W_rel + b + h @ W_root )
// Block = 256 threads = 2 nodes x 128 output channels.  Safe for out == h
// (each block stages its own rows in LDS before writing).
// ---------------------------------------------------------------------------
template <bool RELU>
__global__ void k_transform(const float* __restrict__ agg,
                            const float* __restrict__ h,
                            const float* __restrict__ W_rel,
                            const float* __restrict__ b,
                            const float* __restrict__ W_root,
                            float* __restrict__ out) {
    int g = threadIdx.x >> 7;
    int c = threadIdx.x & 127;
    int node = blockIdx.x * 2 + g;

    __shared__ float sa[2][C];
    __shared__ float sh[2][C];

    if (node < NN) {
        sa[g][c] = agg[(size_t)node * C + c];
        sh[g][c] = h[(size_t)node * C + c];
    }
    __syncthreads();
    if (node >= NN) return;

    float acc = b[c];
#pragma unroll 8
    for (int k = 0; k < C; ++k) {
        acc += sa[g][k] * W_rel[k * C + c];
        acc += sh[g][k] * W_root[k * C + c];
    }
    if (RELU) acc = fmaxf(acc, 0.0f);
    out[(size_t)node * C + c] = acc;
}

// ---------------------------------------------------------------------------
// Mean-pool + final linear
// ---------------------------------------------------------------------------
__global__ void k_pool(const float* __restrict__ h,
                       const int* __restrict__ batch,
                       float* __restrict__ sums) {
    int t = blockIdx.x * blockDim.x + threadIdx.x;
    if (t >= NN * C) return;
    int node = t >> 7;
    int c = t & 127;
    atomicAdd(sums + batch[node] * C + c, h[t]);
}

__global__ void k_count(const int* __restrict__ batch,
                        float* __restrict__ counts) {
    int i = blockIdx.x * blockDim.x + threadIdx.x;
    if (i < NN) atomicAdd(counts + batch[i], 1.0f);
}

__global__ void k_final(const float* __restrict__ sums,
                        const float* __restrict__ counts,
                        const float* __restrict__ W_lin,
                        const float* __restrict__ b_lin,
                        float* __restrict__ out) {
    int g = blockIdx.x;
    int t = threadIdx.x;
    __shared__ float sp[C];
    float cnt = fmaxf(counts[g], 1.0f);
    sp[t] = sums[(size_t)g * C + t] / cnt;
    __syncthreads();
    if (t < OC) {
        float acc = b_lin[t];
#pragma unroll 8
        for (int k = 0; k < C; ++k) acc += sp[k] * W_lin[k * OC + t];
        out[(size_t)g * OC + t] = acc;
    }
}

extern "C" void kernel_launch(void* const* d_in, const int* in_sizes, int n_in,
                              void* d_out, int out_size, void* d_ws, size_t ws_size,
                              hipStream_t stream) {
    const float* x       = (const float*)d_in[0];
    const int*   eidx    = (const int*)d_in[1];
    const int*   batch   = (const int*)d_in[2];
    const float* W1_rel  = (const float*)d_in[3];
    const float* b1      = (const float*)d_in[4];
    const float* W1_root = (const float*)d_in[5];
    const float* W2_rel  = (const float*)d_in[6];
    const float* b2      = (const float*)d_in[7];
    const float* W2_root = (const float*)d_in[8];
    const float* W3_rel  = (const float*)d_in[9];
    const float* b3      = (const float*)d_in[10];
    const float* W3_root = (const float*)d_in[11];
    const float* W_lin   = (const float*)d_in[12];
    const float* b_lin   = (const float*)d_in[13];
    float* out = (float*)d_out;

    const int* src = eidx;
    const int* dst = eidx + NE;

    // Workspace layout
    float* agg    = (float*)d_ws;                   // NN*C floats
    float* hA     = agg + (size_t)NN * C;           // NN*C floats
    float* sums   = hA + (size_t)NN * C;            // NG*C floats
    float* counts = sums + (size_t)NG * C;          // NG floats
    int*   deg    = (int*)(counts + NG);            // NN ints (also scratch)
    int*   rp     = deg + NN;                       // NN+1 ints
    int*   cursor = rp + NN + 1;                    // NN ints
    int*   csr    = cursor + NN;                    // NE ints
    int*   bsum   = csr + NE;                       // NB ints

    const int eb = (NE + 255) / 256;                // edge-parallel blocks
    const int gb = (NN * 32 + 255) / 256;           // gather blocks
    const int tr_blocks = (NN + 1) / 2;
    const int pool_blocks = (NN * C + 255) / 256;

    // ---- CSR build (once; shared by all 3 layers) ----
    hipMemsetAsync(deg, 0, NN * sizeof(int), stream);
    k_hist<<<eb, 256, 0, stream>>>(dst, deg);
    k_scan1<<<NB, SCAN_B, 0, stream>>>(deg, rp, bsum);
    k_scan2<<<1, 64, 0, stream>>>(bsum);
    k_scan3<<<NB, SCAN_B, 0, stream>>>(rp, bsum, cursor);
    k_fill<<<eb, 256, 0, stream>>>(src, dst, cursor, csr);

    // ---- Layer 1 ----
    k_gather<<<gb, 256, 0, stream>>>(x, rp, csr, agg);
    k_transform<true><<<tr_blocks, 256, 0, stream>>>(agg, x, W1_rel, b1, W1_root, hA);

    // ---- Layer 2 (in-place transform) ----
    k_gather<<<gb, 256, 0, stream>>>(hA, rp, csr, agg);
    k_transform<true><<<tr_blocks, 256, 0, stream>>>(agg, hA, W2_rel, b2, W2_root, hA);

    // ---- Layer 3 (no relu, in-place) ----
    k_gather<<<gb, 256, 0, stream>>>(hA, rp, csr, agg);
    k_transform<false><<<tr_blocks, 256, 0, stream>>>(agg, hA, W3_rel, b3, W3_root, hA);

    // ---- Pool + final linear ----
    hipMemsetAsync(sums, 0, ((size_t)NG * C + NG) * sizeof(float), stream);
    k_pool<<<pool_blocks, 256, 0, stream>>>(hA, batch, sums);
    k_count<<<(NN + 255) / 256, 256, 0, stream>>>(batch, counts);
    k_final<<<NG, C, 0, stream>>>(sums, counts, W_lin, b_lin, out);
}

// Round 3
// 584.056 us; speedup vs baseline: 16.1430x; 3.0810x over previous
//
#include <hip/hip_runtime.h>

static constexpr int NN = 100000;   // nodes
static constexpr int NE = 1600000;  // edges
static constexpr int C  = 128;      // feature dim
static constexpr int OC = 10;      // output classes
static constexpr int NG = 512;      // graphs

static constexpr int SCAN_B = 1024;
static constexpr int NB = (NN + SCAN_B - 1) / SCAN_B;  // 98

typedef unsigned short u16;
typedef __attribute__((ext_vector_type(8))) short short8;   // 8 bf16 = 16B
typedef __attribute__((ext_vector_type(8))) short bf16x8;   // MFMA A/B frag
typedef __attribute__((ext_vector_type(4))) float f32x4;    // MFMA C/D frag

__device__ __forceinline__ float bf2f(u16 u) {
    union { float f; unsigned int u32; } v; v.u32 = ((unsigned int)u) << 16; return v.f;
}
__device__ __forceinline__ u16 f2bf(float f) {
    union { float f; unsigned int u; } v; v.f = f;
    unsigned int u = v.u;
    unsigned int r = u + 0x7FFF + ((u >> 16) & 1);   // RNE
    return (u16)(r >> 16);
}

// ---------------------------------------------------------------------------
// CSR build: deg histogram -> exclusive scan -> cursor fill
// ---------------------------------------------------------------------------
__global__ void k_hist(const int* __restrict__ dst, int* __restrict__ deg) {
    int e = blockIdx.x * blockDim.x + threadIdx.x;
    if (e < NE) atomicAdd(&deg[dst[e]], 1);
}

__global__ void k_scan1(const int* __restrict__ deg, int* __restrict__ rp,
                        int* __restrict__ bsum) {
    __shared__ int buf[SCAN_B];
    int tid = threadIdx.x;
    int i = blockIdx.x * SCAN_B + tid;
    int v = (i < NN) ? deg[i] : 0;
    buf[tid] = v;
    __syncthreads();
    for (int off = 1; off < SCAN_B; off <<= 1) {
        int t = (tid >= off) ? buf[tid - off] : 0;
        __syncthreads();
        buf[tid] += t;
        __syncthreads();
    }
    if (i < NN) rp[i] = buf[tid] - v;  // exclusive
    if (tid == SCAN_B - 1) bsum[blockIdx.x] = buf[tid];
}

__global__ void k_scan2(int* __restrict__ bsum) {
    if (blockIdx.x == 0 && threadIdx.x == 0) {
        int acc = 0;
        for (int i = 0; i < NB; ++i) { int t = bsum[i]; bsum[i] = acc; acc += t; }
    }
}

__global__ void k_scan3(int* __restrict__ rp, const int* __restrict__ bsum,
                        int* __restrict__ cursor) {
    int i = blockIdx.x * SCAN_B + threadIdx.x;
    if (i < NN) {
        int v = rp[i] + bsum[i / SCAN_B];
        rp[i] = v;
        cursor[i] = v;
    }
    if (i == 0) rp[NN] = NE;
}

__global__ void k_fill(const int* __restrict__ src, const int* __restrict__ dst,
                       int* __restrict__ cursor, int* __restrict__ csr) {
    int e = blockIdx.x * blockDim.x + threadIdx.x;
    if (e < NE) {
        int p = atomicAdd(&cursor[dst[e]], 1);
        csr[p] = src[e];
    }
}

// ---------------------------------------------------------------------------
// f32 -> bf16 conversion (8 elems/thread)
// ---------------------------------------------------------------------------
__global__ void k_cvt_bf16(const float* __restrict__ in, u16* __restrict__ out) {
    int i = blockIdx.x * blockDim.x + threadIdx.x;
    size_t base = (size_t)i * 8;
    if (base >= (size_t)NN * C) return;
    float4 a = *reinterpret_cast<const float4*>(in + base);
    float4 b = *reinterpret_cast<const float4*>(in + base + 4);
    u16 o[8] = { f2bf(a.x), f2bf(a.y), f2bf(a.z), f2bf(a.w),
                 f2bf(b.x), f2bf(b.y), f2bf(b.z), f2bf(b.w) };
    *reinterpret_cast<short8*>(out + base) = *reinterpret_cast<const short8*>(o);
}

// ---------------------------------------------------------------------------
// Pack [W_rel; W_root] (256x128 f32) into per-lane MFMA B-fragment order, bf16.
// Bp[((kk*8 + nfrag)*64 + lane)*8 + j] = Wcat[kk*32 + (lane>>4)*8 + j][nfrag*16 + (lane&15)]
// ---------------------------------------------------------------------------
__global__ void k_pack_w(const float* __restrict__ W_rel,
                         const float* __restrict__ W_root,
                         u16* __restrict__ Bp) {
    int t = blockIdx.x * blockDim.x + threadIdx.x;   // 0..4095
    if (t >= 4096) return;
    int lane = t & 63;
    int nfrag = (t >> 6) & 7;
    int kk = t >> 9;
    int col = nfrag * 16 + (lane & 15);
    int k0 = kk * 32 + (lane >> 4) * 8;
    u16 vals[8];
#pragma unroll
    for (int j = 0; j < 8; ++j) {
        int k = k0 + j;
        float w = (k < C) ? W_rel[k * C + col] : W_root[(k - C) * C + col];
        vals[j] = f2bf(w);
    }
    *reinterpret_cast<short8*>(Bp + (size_t)t * 8) = *reinterpret_cast<const short8*>(vals);
}

// ---------------------------------------------------------------------------
// Gather-aggregate (bf16): agg[i] = sum_{j in in(i)} h[j].  16 lanes/node.
// ---------------------------------------------------------------------------
__global__ void k_gather(const u16* __restrict__ h, const int* __restrict__ rp,
                         const int* __restrict__ csr, u16* __restrict__ agg) {
    int t = blockIdx.x * blockDim.x + threadIdx.x;
    int node = t >> 4;
    if (node >= NN) return;
    int seg = (t & 15) * 8;   // element offset within row
    int beg = rp[node], end = rp[node + 1];
    float acc[8] = {};
    for (int j = beg; j < end; ++j) {
        int s = csr[j];
        short8 v = *reinterpret_cast<const short8*>(h + (size_t)s * C + seg);
#pragma unroll
        for (int q = 0; q < 8; ++q) acc[q] += bf2f((u16)v[q]);
    }
    u16 o[8];
#pragma unroll
    for (int q = 0; q < 8; ++q) o[q] = f2bf(acc[q]);
    *reinterpret_cast<short8*>(agg + (size_t)node * C + seg) = *reinterpret_cast<const short8*>(o);
}

// ---------------------------------------------------------------------------
// MFMA transform: out = [relu]( [agg|h] @ [W_rel;W_root] + b ), bf16 in/out.
// Block = 4 waves x 16 rows = 64 nodes; wave computes 16 x 128.
// Safe in-place (out == h): each block only reads/writes its own rows.
// ---------------------------------------------------------------------------
template <bool RELU>
__global__ __launch_bounds__(256) void k_transform_mfma(
    const u16* __restrict__ agg, const u16* __restrict__ h,
    const u16* __restrict__ Bp, const float* __restrict__ bias,
    u16* __restrict__ out) {
    int wave = threadIdx.x >> 6;
    int lane = threadIdx.x & 63;
    int row0 = blockIdx.x * 64 + wave * 16;
    int arow = row0 + (lane & 15);
    int rclamp = arow < NN ? arow : NN - 1;
    int koff = (lane >> 4) * 8;

    f32x4 acc[8] = {};
#pragma unroll
    for (int kk = 0; kk < 8; ++kk) {
        bf16x8 a;
        if (kk < 4) {
            a = *reinterpret_cast<const bf16x8*>(agg + (size_t)rclamp * C + kk * 32 + koff);
        } else {
            a = *reinterpret_cast<const bf16x8*>(h + (size_t)rclamp * C + (kk - 4) * 32 + koff);
        }
        const u16* bp = Bp + ((size_t)kk * 8 * 64 + lane) * 8;
#pragma unroll
        for (int n = 0; n < 8; ++n) {
            bf16x8 b = *reinterpret_cast<const bf16x8*>(bp + (size_t)n * 64 * 8);
            acc[n] = __builtin_amdgcn_mfma_f32_16x16x32_bf16(a, b, acc[n], 0, 0, 0);
        }
    }
    // D layout: col = lane&15 (within 16-col frag), row = row0 + (lane>>4)*4 + r
    int colbase = lane & 15;
    int rowe = row0 + (lane >> 4) * 4;
#pragma unroll
    for (int n = 0; n < 8; ++n) {
        int col = n * 16 + colbase;
        float bb = bias[col];
#pragma unroll
        for (int r = 0; r < 4; ++r) {
            int ro = rowe + r;
            if (ro < NN) {
                float v = acc[n][r] + bb;
                if (RELU) v = fmaxf(v, 0.0f);
                out[(size_t)ro * C + col] = f2bf(v);
            }
        }
    }
}

// ---------------------------------------------------------------------------
// Graph boundaries via binary search (batch is sorted), then fused pool+linear.
// ---------------------------------------------------------------------------
__global__ void k_gbounds(const int* __restrict__ batch, int* __restrict__ gstart) {
    int g = blockIdx.x * blockDim.x + threadIdx.x;
    if (g > NG) return;
    int lo = 0, hi = NN;
    while (lo < hi) { int mid = (lo + hi) >> 1; if (batch[mid] < g) lo = mid + 1; else hi = mid; }
    gstart[g] = lo;
}

__global__ void k_pool_final(const u16* __restrict__ h, const int* __restrict__ gstart,
                             const float* __restrict__ W_lin, const float* __restrict__ b_lin,
                             float* __restrict__ out) {
    int g = blockIdx.x;
    int c = threadIdx.x;  // 128 threads
    int s = gstart[g], e = gstart[g + 1];
    float acc = 0.0f;
    for (int i = s; i < e; ++i) acc += bf2f(h[(size_t)i * C + c]);
    __shared__ float sp[C];
    float cnt = (float)max(e - s, 1);
    sp[c] = acc / cnt;
    __syncthreads();
    if (c < OC) {
        float o = b_lin[c];
#pragma unroll 8
        for (int k = 0; k < C; ++k) o += sp[k] * W_lin[k * OC + c];
        out[g * OC + c] = o;
    }
}

extern "C" void kernel_launch(void* const* d_in, const int* in_sizes, int n_in,
                              void* d_out, int out_size, void* d_ws, size_t ws_size,
                              hipStream_t stream) {
    const float* x       = (const float*)d_in[0];
    const int*   eidx    = (const int*)d_in[1];
    const int*   batch   = (const int*)d_in[2];
    const float* W1_rel  = (const float*)d_in[3];
    const float* b1      = (const float*)d_in[4];
    const float* W1_root = (const float*)d_in[5];
    const float* W2_rel  = (const float*)d_in[6];
    const float* b2      = (const float*)d_in[7];
    const float* W2_root = (const float*)d_in[8];
    const float* W3_rel  = (const float*)d_in[9];
    const float* b3      = (const float*)d_in[10];
    const float* W3_root = (const float*)d_in[11];
    const float* W_lin   = (const float*)d_in[12];
    const float* b_lin   = (const float*)d_in[13];
    float* out = (float*)d_out;

    const int* src = eidx;
    const int* dst = eidx + NE;

    // Workspace layout
    u16* xb   = (u16*)d_ws;                       // NN*C bf16
    u16* hb   = xb + (size_t)NN * C;              // NN*C bf16
    u16* aggb = hb + (size_t)NN * C;              // NN*C bf16
    u16* Bp   = aggb + (size_t)NN * C;            // 3 * 32768 bf16 (packed weights)
    int* deg    = (int*)(Bp + 3 * 32768);         // NN
    int* rp     = deg + NN;                       // NN+1
    int* cursor = rp + NN + 1;                    // NN
    int* csr    = cursor + NN;                    // NE
    int* bsum   = csr + NE;                       // NB
    int* gstart = bsum + NB;                      // NG+1

    const int eb = (NE + 255) / 256;
    const int gb = (NN * 16 + 255) / 256;         // gather blocks (16 lanes/node)
    const int tb = (NN + 63) / 64;                // transform blocks
    const int cvtb = ((NN * C / 8) + 255) / 256;

    // ---- CSR build (shared by all 3 layers) ----
    hipMemsetAsync(deg, 0, NN * sizeof(int), stream);
    k_hist<<<eb, 256, 0, stream>>>(dst, deg);
    k_scan1<<<NB, SCAN_B, 0, stream>>>(deg, rp, bsum);
    k_scan2<<<1, 64, 0, stream>>>(bsum);
    k_scan3<<<NB, SCAN_B, 0, stream>>>(rp, bsum, cursor);
    k_fill<<<eb, 256, 0, stream>>>(src, dst, cursor, csr);

    // ---- Precompute: x->bf16, packed weights, graph bounds ----
    k_cvt_bf16<<<cvtb, 256, 0, stream>>>(x, xb);
    k_pack_w<<<16, 256, 0, stream>>>(W1_rel, W1_root, Bp);
    k_pack_w<<<16, 256, 0, stream>>>(W2_rel, W2_root, Bp + 32768);
    k_pack_w<<<16, 256, 0, stream>>>(W3_rel, W3_root, Bp + 2 * 32768);
    k_gbounds<<<3, 256, 0, stream>>>(batch, gstart);

    // ---- Layer 1 ----
    k_gather<<<gb, 256, 0, stream>>>(xb, rp, csr, aggb);
    k_transform_mfma<true><<<tb, 256, 0, stream>>>(aggb, xb, Bp, b1, hb);

    // ---- Layer 2 (in-place) ----
    k_gather<<<gb, 256, 0, stream>>>(hb, rp, csr, aggb);
    k_transform_mfma<true><<<tb, 256, 0, stream>>>(aggb, hb, Bp + 32768, b2, hb);

    // ---- Layer 3 (no relu, in-place) ----
    k_gather<<<gb, 256, 0, stream>>>(hb, rp, csr, aggb);
    k_transform_mfma<false><<<tb, 256, 0, stream>>>(aggb, hb, Bp + 2 * 32768, b3, hb);

    // ---- Fused pool + final linear ----
    k_pool_final<<<NG, C, 0, stream>>>(hb, gstart, W_lin, b_lin, out);
}

// Round 4
// 452.001 us; speedup vs baseline: 20.8593x; 1.2922x over previous
//
#include <hip/hip_runtime.h>

static constexpr int NN = 100000;   // nodes
static constexpr int NE = 1600000;  // edges
static constexpr int C  = 128;      // feature dim
static constexpr int OC = 10;       // output classes
static constexpr int NG = 512;      // graphs

// Bucketed CSR build parameters
static constexpr int BSH  = 9;                         // 512 nodes per bucket
static constexpr int BNW  = 1 << BSH;                  // 512
static constexpr int BK   = (NN + BNW - 1) / BNW;      // 196 buckets
static constexpr int BCAP = 12288;                     // slab capacity (avg ~8163)
static constexpr int EPB  = 8192;                      // edges per binA block
static constexpr int ABLK = (NE + EPB - 1) / EPB;      // 196

typedef unsigned short u16;
typedef __attribute__((ext_vector_type(8))) short short8;   // 8 bf16 = 16B
typedef __attribute__((ext_vector_type(8))) short bf16x8;   // MFMA A/B frag
typedef __attribute__((ext_vector_type(4))) float f32x4;    // MFMA C/D frag

__device__ __forceinline__ float bf2f(u16 u) {
    union { float f; unsigned int u32; } v; v.u32 = ((unsigned int)u) << 16; return v.f;
}
__device__ __forceinline__ u16 f2bf(float f) {
    union { float f; unsigned int u; } v; v.f = f;
    unsigned int u = v.u;
    unsigned int r = u + 0x7FFF + ((u >> 16) & 1);   // RNE
    return (u16)(r >> 16);
}

// ---------------------------------------------------------------------------
// Phase A: bin edges into BK buckets by dst>>BSH.  Per-block LDS histogram,
// one global atomic reservation per (block,bucket), grouped slab writes so
// each slab chunk is written by exactly one block (one XCD) -> no partial-line
// writeback amplification.
// ---------------------------------------------------------------------------
__global__ __launch_bounds__(256) void k_binA(const int* __restrict__ src,
                                              const int* __restrict__ dst,
                                              int* __restrict__ gcnt,
                                              int* __restrict__ buck) {
    __shared__ int cnt[BK];
    __shared__ int curs[BK];
    int tid = threadIdx.x;
    for (int i = tid; i < BK; i += 256) cnt[i] = 0;
    __syncthreads();
    int e0 = blockIdx.x * EPB;
    for (int i = tid; i < EPB; i += 256) {
        int e = e0 + i;
        if (e < NE) atomicAdd(&cnt[dst[e] >> BSH], 1);
    }
    __syncthreads();
    for (int i = tid; i < BK; i += 256) {
        int c = cnt[i];
        int gb = (c > 0) ? atomicAdd(&gcnt[i], c) : 0;
        curs[i] = i * BCAP + gb;
    }
    __syncthreads();
    for (int i = tid; i < EPB; i += 256) {
        int e = e0 + i;
        if (e < NE) {
            int d = dst[e];
            int b = d >> BSH;
            int p = atomicAdd(&curs[b], 1);
            if (p < (b + 1) * BCAP)               // slab overflow guard
                buck[p] = (src[e] << BSH) | (d & (BNW - 1));
        }
    }
}

// ---------------------------------------------------------------------------
// Exclusive scan of bucket counts -> per-bucket CSR base.  Also rp[NN]=NE.
// ---------------------------------------------------------------------------
__global__ void k_binscan(const int* __restrict__ gcnt, int* __restrict__ csrbase,
                          int* __restrict__ rp) {
    __shared__ int buf[256];
    int tid = threadIdx.x;
    int v = (tid < BK) ? gcnt[tid] : 0;
    buf[tid] = v;
    __syncthreads();
    for (int off = 1; off < 256; off <<= 1) {
        int t = (tid >= off) ? buf[tid - off] : 0;
        __syncthreads();
        buf[tid] += t;
        __syncthreads();
    }
    if (tid < BK) csrbase[tid] = buf[tid] - v;
    if (tid == 0) rp[NN] = NE;
}

// ---------------------------------------------------------------------------
// Phase B: one block per bucket.  LDS histogram over the bucket's 512 nodes,
// LDS scan -> rp slice (replaces global hist+scan), then LDS-cursor scatter
// into the bucket's contiguous CSR window (single block -> L2-local writes).
// ---------------------------------------------------------------------------
__global__ __launch_bounds__(BNW) void k_binB(const int* __restrict__ gcnt,
                                              const int* __restrict__ csrbase,
                                              const int* __restrict__ buck,
                                              int* __restrict__ rp,
                                              int* __restrict__ csr) {
    int b = blockIdx.x;
    int tid = threadIdx.x;
    __shared__ int hist[BNW];     // histogram, then cursor
    __shared__ int scanbuf[BNW];
    int n = gcnt[b];
    if (n > BCAP) n = BCAP;
    int base = csrbase[b];
    const int* bb = buck + (size_t)b * BCAP;

    hist[tid] = 0;
    __syncthreads();
    for (int i = tid; i < n; i += BNW) atomicAdd(&hist[bb[i] & (BNW - 1)], 1);
    __syncthreads();

    int v = hist[tid];
    scanbuf[tid] = v;
    __syncthreads();
    for (int off = 1; off < BNW; off <<= 1) {
        int t = (tid >= off) ? scanbuf[tid - off] : 0;
        __syncthreads();
        scanbuf[tid] += t;
        __syncthreads();
    }
    int excl = scanbuf[tid] - v;
    int node = (b << BSH) + tid;
    if (node < NN) rp[node] = base + excl;
    __syncthreads();
    hist[tid] = base + excl;      // cursor
    __syncthreads();
    for (int i = tid; i < n; i += BNW) {
        int en = bb[i];
        int p = atomicAdd(&hist[en & (BNW - 1)], 1);
        csr[p] = en >> BSH;
    }
}

// ---------------------------------------------------------------------------
// f32 -> bf16 conversion (8 elems/thread)
// ---------------------------------------------------------------------------
__global__ void k_cvt_bf16(const float* __restrict__ in, u16* __restrict__ out) {
    int i = blockIdx.x * blockDim.x + threadIdx.x;
    size_t base = (size_t)i * 8;
    if (base >= (size_t)NN * C) return;
    float4 a = *reinterpret_cast<const float4*>(in + base);
    float4 b = *reinterpret_cast<const float4*>(in + base + 4);
    u16 o[8] = { f2bf(a.x), f2bf(a.y), f2bf(a.z), f2bf(a.w),
                 f2bf(b.x), f2bf(b.y), f2bf(b.z), f2bf(b.w) };
    *reinterpret_cast<short8*>(out + base) = *reinterpret_cast<const short8*>(o);
}

// ---------------------------------------------------------------------------
// Pack [W_rel; W_root] (256x128 f32) into per-lane MFMA B-fragment order, bf16.
// ---------------------------------------------------------------------------
__global__ void k_pack_w(const float* __restrict__ W_rel,
                         const float* __restrict__ W_root,
                         u16* __restrict__ Bp) {
    int t = blockIdx.x * blockDim.x + threadIdx.x;   // 0..4095
    if (t >= 4096) return;
    int lane = t & 63;
    int nfrag = (t >> 6) & 7;
    int kk = t >> 9;
    int col = nfrag * 16 + (lane & 15);
    int k0 = kk * 32 + (lane >> 4) * 8;
    u16 vals[8];
#pragma unroll
    for (int j = 0; j < 8; ++j) {
        int k = k0 + j;
        float w = (k < C) ? W_rel[k * C + col] : W_root[(k - C) * C + col];
        vals[j] = f2bf(w);
    }
    *reinterpret_cast<short8*>(Bp + (size_t)t * 8) = *reinterpret_cast<const short8*>(vals);
}

// ---------------------------------------------------------------------------
// Gather-aggregate (bf16): agg[i] = sum_{j in in(i)} h[j].  16 lanes/node.
// ---------------------------------------------------------------------------
__global__ void k_gather(const u16* __restrict__ h, const int* __restrict__ rp,
                         const int* __restrict__ csr, u16* __restrict__ agg) {
    int t = blockIdx.x * blockDim.x + threadIdx.x;
    int node = t >> 4;
    if (node >= NN) return;
    int seg = (t & 15) * 8;   // element offset within row
    int beg = rp[node], end = rp[node + 1];
    float acc[8] = {};
    for (int j = beg; j < end; ++j) {
        int s = csr[j];
        short8 v = *reinterpret_cast<const short8*>(h + (size_t)s * C + seg);
#pragma unroll
        for (int q = 0; q < 8; ++q) acc[q] += bf2f((u16)v[q]);
    }
    u16 o[8];
#pragma unroll
    for (int q = 0; q < 8; ++q) o[q] = f2bf(acc[q]);
    *reinterpret_cast<short8*>(agg + (size_t)node * C + seg) = *reinterpret_cast<const short8*>(o);
}

// ---------------------------------------------------------------------------
// MFMA transform: out = [relu]( [agg|h] @ [W_rel;W_root] + b ), bf16 in/out.
// Block = 4 waves x 16 rows = 64 nodes; wave computes 16 x 128.
// Safe in-place (out == h): each block only reads/writes its own rows.
// ---------------------------------------------------------------------------
template <bool RELU>
__global__ __launch_bounds__(256) void k_transform_mfma(
    const u16* __restrict__ agg, const u16* __restrict__ h,
    const u16* __restrict__ Bp, const float* __restrict__ bias,
    u16* __restrict__ out) {
    int wave = threadIdx.x >> 6;
    int lane = threadIdx.x & 63;
    int row0 = blockIdx.x * 64 + wave * 16;
    int arow = row0 + (lane & 15);
    int rclamp = arow < NN ? arow : NN - 1;
    int koff = (lane >> 4) * 8;

    f32x4 acc[8] = {};
#pragma unroll
    for (int kk = 0; kk < 8; ++kk) {
        bf16x8 a;
        if (kk < 4) {
            a = *reinterpret_cast<const bf16x8*>(agg + (size_t)rclamp * C + kk * 32 + koff);
        } else {
            a = *reinterpret_cast<const bf16x8*>(h + (size_t)rclamp * C + (kk - 4) * 32 + koff);
        }
        const u16* bp = Bp + ((size_t)kk * 8 * 64 + lane) * 8;
#pragma unroll
        for (int n = 0; n < 8; ++n) {
            bf16x8 b = *reinterpret_cast<const bf16x8*>(bp + (size_t)n * 64 * 8);
            acc[n] = __builtin_amdgcn_mfma_f32_16x16x32_bf16(a, b, acc[n], 0, 0, 0);
        }
    }
    int colbase = lane & 15;
    int rowe = row0 + (lane >> 4) * 4;
#pragma unroll
    for (int n = 0; n < 8; ++n) {
        int col = n * 16 + colbase;
        float bb = bias[col];
#pragma unroll
        for (int r = 0; r < 4; ++r) {
            int ro = rowe + r;
            if (ro < NN) {
                float v = acc[n][r] + bb;
                if (RELU) v = fmaxf(v, 0.0f);
                out[(size_t)ro * C + col] = f2bf(v);
            }
        }
    }
}

// ---------------------------------------------------------------------------
// Graph boundaries via binary search (batch is sorted), then fused pool+linear.
// ---------------------------------------------------------------------------
__global__ void k_gbounds(const int* __restrict__ batch, int* __restrict__ gstart) {
    int g = blockIdx.x * blockDim.x + threadIdx.x;
    if (g > NG) return;
    int lo = 0, hi = NN;
    while (lo < hi) { int mid = (lo + hi) >> 1; if (batch[mid] < g) lo = mid + 1; else hi = mid; }
    gstart[g] = lo;
}

__global__ void k_pool_final(const u16* __restrict__ h, const int* __restrict__ gstart,
                             const float* __restrict__ W_lin, const float* __restrict__ b_lin,
                             float* __restrict__ out) {
    int g = blockIdx.x;
    int c = threadIdx.x;  // 128 threads
    int s = gstart[g], e = gstart[g + 1];
    float acc = 0.0f;
    for (int i = s; i < e; ++i) acc += bf2f(h[(size_t)i * C + c]);
    __shared__ float sp[C];
    float cnt = (float)max(e - s, 1);
    sp[c] = acc / cnt;
    __syncthreads();
    if (c < OC) {
        float o = b_lin[c];
#pragma unroll 8
        for (int k = 0; k < C; ++k) o += sp[k] * W_lin[k * OC + c];
        out[g * OC + c] = o;
    }
}

extern "C" void kernel_launch(void* const* d_in, const int* in_sizes, int n_in,
                              void* d_out, int out_size, void* d_ws, size_t ws_size,
                              hipStream_t stream) {
    const float* x       = (const float*)d_in[0];
    const int*   eidx    = (const int*)d_in[1];
    const int*   batch   = (const int*)d_in[2];
    const float* W1_rel  = (const float*)d_in[3];
    const float* b1      = (const float*)d_in[4];
    const float* W1_root = (const float*)d_in[5];
    const float* W2_rel  = (const float*)d_in[6];
    const float* b2      = (const float*)d_in[7];
    const float* W2_root = (const float*)d_in[8];
    const float* W3_rel  = (const float*)d_in[9];
    const float* b3      = (const float*)d_in[10];
    const float* W3_root = (const float*)d_in[11];
    const float* W_lin   = (const float*)d_in[12];
    const float* b_lin   = (const float*)d_in[13];
    float* out = (float*)d_out;

    const int* src = eidx;
    const int* dst = eidx + NE;

    // Workspace layout
    u16* xb   = (u16*)d_ws;                       // NN*C bf16
    u16* hb   = xb + (size_t)NN * C;              // NN*C bf16
    u16* aggb = hb + (size_t)NN * C;              // NN*C bf16
    u16* Bp   = aggb + (size_t)NN * C;            // 3 * 32768 bf16
    int* rp      = (int*)(Bp + 3 * 32768);        // NN+1
    int* csr     = rp + NN + 1;                   // NE
    int* buck    = csr + NE;                      // BK*BCAP
    int* gcnt    = buck + (size_t)BK * BCAP;      // BK
    int* csrbase = gcnt + BK;                     // BK
    int* gstart  = csrbase + BK;                  // NG+1

    const int gb = (NN * 16 + 255) / 256;         // gather blocks (16 lanes/node)
    const int tb = (NN + 63) / 64;                // transform blocks
    const int cvtb = ((NN * C / 8) + 255) / 256;

    // ---- Bucketed CSR build (shared by all 3 layers) ----
    hipMemsetAsync(gcnt, 0, BK * sizeof(int), stream);
    k_binA<<<ABLK, 256, 0, stream>>>(src, dst, gcnt, buck);
    k_binscan<<<1, 256, 0, stream>>>(gcnt, csrbase, rp);
    k_binB<<<BK, BNW, 0, stream>>>(gcnt, csrbase, buck, rp, csr);

    // ---- Precompute: x->bf16, packed weights, graph bounds ----
    k_cvt_bf16<<<cvtb, 256, 0, stream>>>(x, xb);
    k_pack_w<<<16, 256, 0, stream>>>(W1_rel, W1_root, Bp);
    k_pack_w<<<16, 256, 0, stream>>>(W2_rel, W2_root, Bp + 32768);
    k_pack_w<<<16, 256, 0, stream>>>(W3_rel, W3_root, Bp + 2 * 32768);
    k_gbounds<<<3, 256, 0, stream>>>(batch, gstart);

    // ---- Layer 1 ----
    k_gather<<<gb, 256, 0, stream>>>(xb, rp, csr, aggb);
    k_transform_mfma<true><<<tb, 256, 0, stream>>>(aggb, xb, Bp, b1, hb);

    // ---- Layer 2 (in-place) ----
    k_gather<<<gb, 256, 0, stream>>>(hb, rp, csr, aggb);
    k_transform_mfma<true><<<tb, 256, 0, stream>>>(aggb, hb, Bp + 32768, b2, hb);

    // ---- Layer 3 (no relu, in-place) ----
    k_gather<<<gb, 256, 0, stream>>>(hb, rp, csr, aggb);
    k_transform_mfma<false><<<tb, 256, 0, stream>>>(aggb, hb, Bp + 2 * 32768, b3, hb);

    // ---- Fused pool + final linear ----
    k_pool_final<<<NG, C, 0, stream>>>(hb, gstart, W_lin, b_lin, out);
}